// Round 3
// baseline (219.206 us; speedup 1.0000x reference)
//
#include <hip/hip_runtime.h>

#define NN 256
#define EHID 14

typedef short short8 __attribute__((ext_vector_type(8)));
typedef float f32x16 __attribute__((ext_vector_type(16)));

__device__ __forceinline__ float sigm(float x) {
    return __builtin_amdgcn_rcpf(1.0f + __expf(-x));
}
// exact RNE f32->bf16 (used for one-time weight fragments)
__device__ __forceinline__ unsigned int bfbits(float f) {
    unsigned int u = __builtin_bit_cast(unsigned int, f);
    return (u + 0x7FFFu + ((u >> 16) & 1u)) >> 16;
}
// hot-loop pack: 2 f32 -> 2 bf16 in one instr
__device__ __forceinline__ unsigned int cvtpk(float lo, float hi) {
    unsigned int r;
    asm("v_cvt_pk_bf16_f32 %0, %1, %2" : "=v"(r) : "v"(lo), "v"(hi));
    return r;
}
__device__ __forceinline__ short8 mk8(unsigned a, unsigned b, unsigned c, unsigned d) {
    int4 t = make_int4((int)a, (int)b, (int)c, (int)d);
    return __builtin_bit_cast(short8, t);
}

__global__ __launch_bounds__(64, 4) void egnn_nolds(
    const float* __restrict__ x,
    const float* __restrict__ W1, const float* __restrict__ b1,
    const float* __restrict__ W2, const float* __restrict__ b2,
    const float* __restrict__ Wg, const float* __restrict__ bg,
    const float* __restrict__ gamma, const float* __restrict__ beta,
    const float* __restrict__ Wn1, const float* __restrict__ bn1,
    const float* __restrict__ Wn2, const float* __restrict__ bn2,
    const int* __restrict__ mask, float* __restrict__ out)
{
    const int l    = threadIdx.x;      // 0..63
    const int l31  = l & 31;
    const int half = l >> 5;
    const int gi   = blockIdx.x;       // one (b,i) per wave
    const int b    = gi >> 8;
    const int i    = gi & 255;

    const float* xb = x + b * (NN * 3);
    const float xi0 = xb[i*3+0], xi1 = xb[i*3+1], xi2 = xb[i*3+2];
    const int   mi  = mask[b*NN + i];

    float pn[6];
#pragma unroll
    for (int u = 0; u < 6; ++u) pn[u] = 0.f;

    if (mi) {
        // per-wave mask bitmaps (wave-uniform SGPRs)
        unsigned long long mb[4];
#pragma unroll
        for (int t = 0; t < 4; ++t)
            mb[t] = __ballot(mask[b*NN + t*64 + l] != 0);

        // ---- A1: W1^T (rows = 14 h-chans, K: k<7 -> W1[k][ch], k==7 -> b1, else 0) ----
        unsigned a1p[4];
#pragma unroll
        for (int e2 = 0; e2 < 4; ++e2) {
            const int k0 = 8*half + 2*e2, k1 = k0 + 1;
            float w0 = 0.f, w1 = 0.f;
            if (l31 < EHID) {
                w0 = (k0 < 7) ? W1[k0*EHID + l31] : ((k0 == 7) ? b1[l31] : 0.f);
                w1 = (k1 < 7) ? W1[k1*EHID + l31] : ((k1 == 7) ? b1[l31] : 0.f);
            }
            a1p[e2] = bfbits(w0) | (bfbits(w1) << 16);
        }
        const short8 A1 = mk8(a1p[0], a1p[1], a1p[2], a1p[3]);

        // ---- A2: W2^T (rows = 64 out-chans in 2 frags, k<14 -> W2, k==14 -> b2, k==15 -> 0) ----
        unsigned a2p[2][4];
#pragma unroll
        for (int mf = 0; mf < 2; ++mf) {
            const int ch = l31 + 32*mf;
#pragma unroll
            for (int e2 = 0; e2 < 4; ++e2) {
                const int k0 = 8*half + 2*e2, k1 = k0 + 1;
                const float w0 = (k0 < EHID) ? W2[k0*64 + ch] : ((k0 == EHID) ? b2[ch] : 0.f);
                const float w1 = (k1 < EHID) ? W2[k1*64 + ch] : ((k1 == EHID) ? b2[ch] : 0.f);
                a2p[mf][e2] = bfbits(w0) | (bfbits(w1) << 16);
            }
        }
        const short8 A20 = mk8(a2p[0][0], a2p[0][1], a2p[0][2], a2p[0][3]);
        const short8 A21 = mk8(a2p[1][0], a2p[1][1], a2p[1][2], a2p[1][3]);

        // gate weights in C/D row layout
        float wgv0[16], wgv1[16];
#pragma unroll
        for (int r = 0; r < 16; ++r) {
            const int row = (r & 3) + 8*(r >> 2) + 4*half;
            wgv0[r] = Wg[row];
            wgv1[r] = Wg[row + 32];
        }

        const float bg0 = bg[0];
        float macc0[16], macc1[16];
#pragma unroll
        for (int r = 0; r < 16; ++r) { macc0[r] = 0.f; macc1[r] = 0.f; }

#pragma unroll
        for (int rnd = 0; rnd < 8; ++rnd) {
            // ---- build edge_in B-frag for 32 edges (both halves compute same; A1 k>=8 rows are 0) ----
            const int e = rnd*32 + l31;
            const float xj0 = xb[e*3+0], xj1 = xb[e*3+1], xj2 = xb[e*3+2];
            const float r0 = xi0-xj0, r1 = xi1-xj1, r2 = xi2-xj2;
            const float rd = r0*r0 + r1*r1 + r2*r2;
            const unsigned p0 = cvtpk(xi0, xi1);
            const unsigned p1 = cvtpk(xi2, xj0);
            const unsigned p2 = cvtpk(xj1, xj2);
            const unsigned p3 = cvtpk(rd, 1.0f);       // k6 = rel_dist, k7 = bias
            const short8 B1 = mk8(p0, p1, p2, p3);

            f32x16 c;
#pragma unroll
            for (int r = 0; r < 16; ++r) c[r] = 0.f;
            c = __builtin_amdgcn_mfma_f32_32x32x16_bf16(A1, B1, c, 0, 0, 0);

            // SiLU on the 8 live rows this half holds (half1 r6,r7 -> rows 14,15 = 0, harmless)
            float s[8];
#pragma unroll
            for (int r = 0; r < 8; ++r) s[r] = c[r] * sigm(c[r]);
            const unsigned q01 = cvtpk(s[0], s[1]);
            const unsigned q23 = cvtpk(s[2], s[3]);
            const unsigned q45 = cvtpk(s[4], s[5]);
            const unsigned q67 = cvtpk(s[6], s[7]);
            // cross-half exchange to assemble layer-2 B-frag (k = h-channel)
            const unsigned sendA = half ? q01 : q45;
            const unsigned sendB = half ? q23 : q67;
            const unsigned recvA = (unsigned)__shfl_xor((int)sendA, 32, 64);
            const unsigned recvB = (unsigned)__shfl_xor((int)sendB, 32, 64);
            const unsigned w0 = half ? recvA : q01;          // k(0,1)  | k(8,9)
            const unsigned w1 = half ? recvB : q23;          // k(2,3)  | k(10,11)
            const unsigned w2 = half ? q45   : recvA;        // k(4,5)  | k(12,13)
            const unsigned w3 = half ? 0x00003F80u : recvB;  // k(6,7)  | k14=1 (b2), k15=0
            const short8 B2 = mk8(w0, w1, w2, w3);

            f32x16 c0, c1;
#pragma unroll
            for (int r = 0; r < 16; ++r) { c0[r] = 0.f; c1[r] = 0.f; }
            c0 = __builtin_amdgcn_mfma_f32_32x32x16_bf16(A20, B2, c0, 0, 0, 0);
            c1 = __builtin_amdgcn_mfma_f32_32x32x16_bf16(A21, B2, c1, 0, 0, 0);

            float v0[16], v1[16];
            float gp = 0.f;
#pragma unroll
            for (int r = 0; r < 16; ++r) {
                v0[r] = c0[r] * sigm(c0[r]);
                gp += v0[r] * wgv0[r];
                v1[r] = c1[r] * sigm(c1[r]);
                gp += v1[r] * wgv1[r];
            }
            const float go = __shfl_xor(gp, 32, 64);
            float g = sigm(gp + go + bg0);
            const unsigned mhw = (unsigned)(mb[rnd >> 1] >> ((rnd & 1) * 32));
            g = ((mhw >> l31) & 1u) ? g : 0.f;
#pragma unroll
            for (int r = 0; r < 16; ++r) {
                macc0[r] += v0[r] * g;
                macc1[r] += v1[r] * g;
            }
        }

        // ---- project per-lane partial m through Wn1 (linear, commutes with edge-sum) ----
#pragma unroll
        for (int r = 0; r < 16; ++r) {
            const int row = (r & 3) + 8*(r >> 2) + 4*half;
            const float m0 = macc0[r], m1 = macc1[r];
            const float* wr0 = Wn1 + (3 + row) * 6;
            const float* wr1 = Wn1 + (3 + row + 32) * 6;
#pragma unroll
            for (int u = 0; u < 6; ++u) pn[u] += m0 * wr0[u] + m1 * wr1[u];
        }
        // butterfly-sum the 6 projections over all 64 lanes
#pragma unroll
        for (int sft = 1; sft <= 32; sft <<= 1) {
#pragma unroll
            for (int u = 0; u < 6; ++u) pn[u] += __shfl_xor(pn[u], sft, 64);
        }
    }

    // ---- node finish (cheap, replicated) ----
    const float mu  = (xi0 + xi1 + xi2) * (1.f/3.f);
    const float d0  = xi0 - mu, d1 = xi1 - mu, d2 = xi2 - mu;
    const float var = (d0*d0 + d1*d1 + d2*d2) * (1.f/3.f);
    const float rs  = rsqrtf(var + 1e-5f);
    const float n0  = d0*rs*gamma[0] + beta[0];
    const float n1  = d1*rs*gamma[1] + beta[1];
    const float n2  = d2*rs*gamma[2] + beta[2];

    float ss[6];
#pragma unroll
    for (int u = 0; u < 6; ++u) {
        const float sv = pn[u] + bn1[u] + n0*Wn1[u] + n1*Wn1[6+u] + n2*Wn1[12+u];
        ss[u] = sv * sigm(sv);
    }
    if (l < 3) {
        const float xres = (l == 0) ? xi0 : ((l == 1) ? xi1 : xi2);
        float sv = bn2[l] + xres;
#pragma unroll
        for (int u = 0; u < 6; ++u) sv += ss[u] * Wn2[u*3 + l];
        out[gi*3 + l] = sv;
    }
}

extern "C" void kernel_launch(void* const* d_in, const int* in_sizes, int n_in,
                              void* d_out, int out_size, void* d_ws, size_t ws_size,
                              hipStream_t stream) {
    (void)in_sizes; (void)n_in; (void)d_ws; (void)ws_size; (void)out_size;
    const float* x     = (const float*)d_in[0];
    const float* W1    = (const float*)d_in[1];
    const float* b1    = (const float*)d_in[2];
    const float* W2    = (const float*)d_in[3];
    const float* b2    = (const float*)d_in[4];
    const float* Wg    = (const float*)d_in[5];
    const float* bg    = (const float*)d_in[6];
    const float* gamma = (const float*)d_in[7];
    const float* beta  = (const float*)d_in[8];
    const float* Wn1   = (const float*)d_in[9];
    const float* bn1   = (const float*)d_in[10];
    const float* Wn2   = (const float*)d_in[11];
    const float* bn2   = (const float*)d_in[12];
    const int*   mask  = (const int*)d_in[13];
    float* out = (float*)d_out;

    dim3 grid(32 * NN);   // 8192 one-wave blocks
    dim3 block(64);
    hipLaunchKernelGGL(egnn_nolds, grid, block, 0, stream,
                       x, W1, b1, W2, b2, Wg, bg, gamma, beta,
                       Wn1, bn1, Wn2, bn2, mask, out);
}

// Round 4
// 45.397 us; speedup vs baseline: 4.8287x; 4.8287x over previous
//
#include <hip/hip_runtime.h>

#define NN 256
#define EHID 14

typedef short short8 __attribute__((ext_vector_type(8)));
typedef float f32x16 __attribute__((ext_vector_type(16)));

__device__ __forceinline__ float sigm(float x) {
    return __builtin_amdgcn_rcpf(1.0f + __expf(-x));
}
// exact RNE f32->bf16 (used for one-time weight fragments)
__device__ __forceinline__ unsigned int bfbits(float f) {
    unsigned int u = __builtin_bit_cast(unsigned int, f);
    return (u + 0x7FFFu + ((u >> 16) & 1u)) >> 16;
}
// hot-loop pack: 2 f32 -> 2 bf16 in one instr
__device__ __forceinline__ unsigned int cvtpk(float lo, float hi) {
    unsigned int r;
    asm("v_cvt_pk_bf16_f32 %0, %1, %2" : "=v"(r) : "v"(lo), "v"(hi));
    return r;
}
__device__ __forceinline__ short8 mk8(unsigned a, unsigned b, unsigned c, unsigned d) {
    int4 t = make_int4((int)a, (int)b, (int)c, (int)d);
    return __builtin_bit_cast(short8, t);
}

// launch_bounds(64, 2): VGPR cap 256 — R3's (64,4) capped VGPR at 64 and
// spilled ~590 MB/dispatch to scratch (FETCH 190MB + WRITE 395MB, rocprof R3).
__global__ __launch_bounds__(64, 2) void egnn_nolds(
    const float* __restrict__ x,
    const float* __restrict__ W1, const float* __restrict__ b1,
    const float* __restrict__ W2, const float* __restrict__ b2,
    const float* __restrict__ Wg, const float* __restrict__ bg,
    const float* __restrict__ gamma, const float* __restrict__ beta,
    const float* __restrict__ Wn1, const float* __restrict__ bn1,
    const float* __restrict__ Wn2, const float* __restrict__ bn2,
    const int* __restrict__ mask, float* __restrict__ out)
{
    const int l    = threadIdx.x;      // 0..63
    const int l31  = l & 31;
    const int half = l >> 5;
    const int gi   = blockIdx.x;       // one (b,i) per wave
    const int b    = gi >> 8;
    const int i    = gi & 255;

    const float* xb = x + b * (NN * 3);
    const float xi0 = xb[i*3+0], xi1 = xb[i*3+1], xi2 = xb[i*3+2];
    const int   mi  = mask[b*NN + i];

    float pn[6];
#pragma unroll
    for (int u = 0; u < 6; ++u) pn[u] = 0.f;

    if (mi) {
        // per-wave mask bitmaps (wave-uniform SGPRs)
        unsigned long long mb[4];
#pragma unroll
        for (int t = 0; t < 4; ++t)
            mb[t] = __ballot(mask[b*NN + t*64 + l] != 0);

        // ---- A1: W1^T (rows = 14 h-chans, K: k<7 -> W1[k][ch], k==7 -> b1, else 0) ----
        unsigned a1p[4];
#pragma unroll
        for (int e2 = 0; e2 < 4; ++e2) {
            const int k0 = 8*half + 2*e2, k1 = k0 + 1;
            float w0 = 0.f, w1 = 0.f;
            if (l31 < EHID) {
                w0 = (k0 < 7) ? W1[k0*EHID + l31] : ((k0 == 7) ? b1[l31] : 0.f);
                w1 = (k1 < 7) ? W1[k1*EHID + l31] : ((k1 == 7) ? b1[l31] : 0.f);
            }
            a1p[e2] = bfbits(w0) | (bfbits(w1) << 16);
        }
        const short8 A1 = mk8(a1p[0], a1p[1], a1p[2], a1p[3]);

        // ---- A2: W2^T (rows = 64 out-chans in 2 frags, k<14 -> W2, k==14 -> b2, k==15 -> 0) ----
        unsigned a2p[2][4];
#pragma unroll
        for (int mf = 0; mf < 2; ++mf) {
            const int ch = l31 + 32*mf;
#pragma unroll
            for (int e2 = 0; e2 < 4; ++e2) {
                const int k0 = 8*half + 2*e2, k1 = k0 + 1;
                const float w0 = (k0 < EHID) ? W2[k0*64 + ch] : ((k0 == EHID) ? b2[ch] : 0.f);
                const float w1 = (k1 < EHID) ? W2[k1*64 + ch] : ((k1 == EHID) ? b2[ch] : 0.f);
                a2p[mf][e2] = bfbits(w0) | (bfbits(w1) << 16);
            }
        }
        const short8 A20 = mk8(a2p[0][0], a2p[0][1], a2p[0][2], a2p[0][3]);
        const short8 A21 = mk8(a2p[1][0], a2p[1][1], a2p[1][2], a2p[1][3]);

        // gate weights in C/D row layout
        float wgv0[16], wgv1[16];
#pragma unroll
        for (int r = 0; r < 16; ++r) {
            const int row = (r & 3) + 8*(r >> 2) + 4*half;
            wgv0[r] = Wg[row];
            wgv1[r] = Wg[row + 32];
        }

        const float bg0 = bg[0];
        float macc0[16], macc1[16];
#pragma unroll
        for (int r = 0; r < 16; ++r) { macc0[r] = 0.f; macc1[r] = 0.f; }

#pragma unroll 2
        for (int rnd = 0; rnd < 8; ++rnd) {
            // ---- build edge_in B-frag for 32 edges (both halves compute same; A1 k>=8 rows are 0) ----
            const int e = rnd*32 + l31;
            const float xj0 = xb[e*3+0], xj1 = xb[e*3+1], xj2 = xb[e*3+2];
            const float r0 = xi0-xj0, r1 = xi1-xj1, r2 = xi2-xj2;
            const float rd = r0*r0 + r1*r1 + r2*r2;
            const unsigned p0 = cvtpk(xi0, xi1);
            const unsigned p1 = cvtpk(xi2, xj0);
            const unsigned p2 = cvtpk(xj1, xj2);
            const unsigned p3 = cvtpk(rd, 1.0f);       // k6 = rel_dist, k7 = bias
            const short8 B1 = mk8(p0, p1, p2, p3);

            f32x16 c;
#pragma unroll
            for (int r = 0; r < 16; ++r) c[r] = 0.f;
            c = __builtin_amdgcn_mfma_f32_32x32x16_bf16(A1, B1, c, 0, 0, 0);

            // SiLU on the 8 live rows this half holds (half1 r6,r7 -> rows 14,15 = 0, harmless)
            float s[8];
#pragma unroll
            for (int r = 0; r < 8; ++r) s[r] = c[r] * sigm(c[r]);
            const unsigned q01 = cvtpk(s[0], s[1]);
            const unsigned q23 = cvtpk(s[2], s[3]);
            const unsigned q45 = cvtpk(s[4], s[5]);
            const unsigned q67 = cvtpk(s[6], s[7]);
            // cross-half exchange to assemble layer-2 B-frag (k = h-channel)
            const unsigned sendA = half ? q01 : q45;
            const unsigned sendB = half ? q23 : q67;
            const unsigned recvA = (unsigned)__shfl_xor((int)sendA, 32, 64);
            const unsigned recvB = (unsigned)__shfl_xor((int)sendB, 32, 64);
            const unsigned w0 = half ? recvA : q01;          // k(0,1)  | k(8,9)
            const unsigned w1 = half ? recvB : q23;          // k(2,3)  | k(10,11)
            const unsigned w2 = half ? q45   : recvA;        // k(4,5)  | k(12,13)
            const unsigned w3 = half ? 0x00003F80u : recvB;  // k(6,7)  | k14=1 (b2), k15=0
            const short8 B2 = mk8(w0, w1, w2, w3);

            f32x16 c0, c1;
#pragma unroll
            for (int r = 0; r < 16; ++r) { c0[r] = 0.f; c1[r] = 0.f; }
            c0 = __builtin_amdgcn_mfma_f32_32x32x16_bf16(A20, B2, c0, 0, 0, 0);
            c1 = __builtin_amdgcn_mfma_f32_32x32x16_bf16(A21, B2, c1, 0, 0, 0);

            float v0[16], v1[16];
            float gp = 0.f;
#pragma unroll
            for (int r = 0; r < 16; ++r) {
                v0[r] = c0[r] * sigm(c0[r]);
                gp += v0[r] * wgv0[r];
                v1[r] = c1[r] * sigm(c1[r]);
                gp += v1[r] * wgv1[r];
            }
            const float go = __shfl_xor(gp, 32, 64);
            float g = sigm(gp + go + bg0);
            const unsigned mhw = (unsigned)(mb[rnd >> 1] >> ((rnd & 1) * 32));
            g = ((mhw >> l31) & 1u) ? g : 0.f;
#pragma unroll
            for (int r = 0; r < 16; ++r) {
                macc0[r] += v0[r] * g;
                macc1[r] += v1[r] * g;
            }
        }

        // ---- project per-lane partial m through Wn1 (linear, commutes with edge-sum) ----
#pragma unroll
        for (int r = 0; r < 16; ++r) {
            const int row = (r & 3) + 8*(r >> 2) + 4*half;
            const float m0 = macc0[r], m1 = macc1[r];
            const float* wr0 = Wn1 + (3 + row) * 6;
            const float* wr1 = Wn1 + (3 + row + 32) * 6;
#pragma unroll
            for (int u = 0; u < 6; ++u) pn[u] += m0 * wr0[u] + m1 * wr1[u];
        }
        // butterfly-sum the 6 projections over all 64 lanes
#pragma unroll
        for (int sft = 1; sft <= 32; sft <<= 1) {
#pragma unroll
            for (int u = 0; u < 6; ++u) pn[u] += __shfl_xor(pn[u], sft, 64);
        }
    }

    // ---- node finish (cheap, replicated) ----
    const float mu  = (xi0 + xi1 + xi2) * (1.f/3.f);
    const float d0  = xi0 - mu, d1 = xi1 - mu, d2 = xi2 - mu;
    const float var = (d0*d0 + d1*d1 + d2*d2) * (1.f/3.f);
    const float rs  = rsqrtf(var + 1e-5f);
    const float n0  = d0*rs*gamma[0] + beta[0];
    const float n1  = d1*rs*gamma[1] + beta[1];
    const float n2  = d2*rs*gamma[2] + beta[2];

    float ss[6];
#pragma unroll
    for (int u = 0; u < 6; ++u) {
        const float sv = pn[u] + bn1[u] + n0*Wn1[u] + n1*Wn1[6+u] + n2*Wn1[12+u];
        ss[u] = sv * sigm(sv);
    }
    if (l < 3) {
        const float xres = (l == 0) ? xi0 : ((l == 1) ? xi1 : xi2);
        float sv = bn2[l] + xres;
#pragma unroll
        for (int u = 0; u < 6; ++u) sv += ss[u] * Wn2[u*3 + l];
        out[gi*3 + l] = sv;
    }
}

extern "C" void kernel_launch(void* const* d_in, const int* in_sizes, int n_in,
                              void* d_out, int out_size, void* d_ws, size_t ws_size,
                              hipStream_t stream) {
    (void)in_sizes; (void)n_in; (void)d_ws; (void)ws_size; (void)out_size;
    const float* x     = (const float*)d_in[0];
    const float* W1    = (const float*)d_in[1];
    const float* b1    = (const float*)d_in[2];
    const float* W2    = (const float*)d_in[3];
    const float* b2    = (const float*)d_in[4];
    const float* Wg    = (const float*)d_in[5];
    const float* bg    = (const float*)d_in[6];
    const float* gamma = (const float*)d_in[7];
    const float* beta  = (const float*)d_in[8];
    const float* Wn1   = (const float*)d_in[9];
    const float* bn1   = (const float*)d_in[10];
    const float* Wn2   = (const float*)d_in[11];
    const float* bn2   = (const float*)d_in[12];
    const int*   mask  = (const int*)d_in[13];
    float* out = (float*)d_out;

    dim3 grid(32 * NN);   // 8192 one-wave blocks
    dim3 block(64);
    hipLaunchKernelGGL(egnn_nolds, grid, block, 0, stream,
                       x, W1, b1, W2, b2, Wg, bg, gamma, beta,
                       Wn1, bn1, Wn2, bn2, mask, out);
}